// Round 1
// baseline (285.246 us; speedup 1.0000x reference)
//
#include <hip/hip_runtime.h>
#include <cstdint>
#include <cstddef>

// Problem constants
#define M_DIM 8192   // batch
#define N_DIM 256    // shared rows (distinct output cols)
#define K_DIM 4096   // in_features
#define OUT_F 4096   // out_features = 16 * N_DIM
// GEMM tiling
#define BM 32
#define BK 64
#define LDK 72       // padded LDS K-stride (halves): +16B breaks 128B-stride bank aliasing
#define S_LD 260     // padded S-tile row stride (floats)

typedef float    float4_ __attribute__((ext_vector_type(4)));
typedef _Float16 half8   __attribute__((ext_vector_type(8)));
typedef unsigned int uint4_ __attribute__((ext_vector_type(4)));

// ---------------------------------------------------------------------------
// Kernel 1: convert shared_weights fp32 -> f16 into workspace (2 MB)
// ---------------------------------------------------------------------------
__global__ __launch_bounds__(256) void convert_w_kernel(const float* __restrict__ w,
                                                        _Float16* __restrict__ wh) {
  int i = (blockIdx.x * 256 + threadIdx.x) * 8;
  float4_ f0 = *(const float4_*)(w + i);
  float4_ f1 = *(const float4_*)(w + i + 4);
  half8 h;
  h[0] = (_Float16)f0[0]; h[1] = (_Float16)f0[1];
  h[2] = (_Float16)f0[2]; h[3] = (_Float16)f0[3];
  h[4] = (_Float16)f1[0]; h[5] = (_Float16)f1[1];
  h[6] = (_Float16)f1[2]; h[7] = (_Float16)f1[3];
  *(half8*)(wh + i) = h;
}

// ---------------------------------------------------------------------------
// Kernel 2: fused S = x @ W^T (MFMA f16) + broadcast-expand + bias -> out
// Each block: 32 batch rows x all 256 N. 256 threads = 4 waves,
// wave w covers n in [w*64, w*64+64): 2 m-frags x 4 n-frags of 16x16x32.
// ---------------------------------------------------------------------------
__global__ __launch_bounds__(256) void swfc_kernel(const float* __restrict__ x,
                                                   const _Float16* __restrict__ wh,
                                                   const float* __restrict__ bias,
                                                   float* __restrict__ out) {
  // staging LDS: As 32x72 f16 (4608 B) + Bs 256x72 f16 (36864 B) = 41472 B
  // epilogue reuses the same space as Sb 32x260 f32 (33280 B)
  __shared__ __align__(16) unsigned char smem[41472];
  _Float16 (*As)[LDK] = (_Float16(*)[LDK])smem;
  _Float16 (*Bs)[LDK] = (_Float16(*)[LDK])(smem + BM * LDK * 2);

  const int tid  = threadIdx.x;
  const int wv   = tid >> 6;        // wave 0..3
  const int lane = tid & 63;
  const int quad = lane >> 4;       // 0..3
  const int l16  = lane & 15;
  const int m0   = blockIdx.x * BM;

  // staging coordinates: thread t handles row (t>>3), 8 elements at col (t&7)*8
  const int arow = tid >> 3;        // 0..31
  const int acol = (tid & 7) * 8;   // 0..56
  const float*    xg  = x  + (size_t)(m0 + arow) * K_DIM + acol;
  const _Float16* wgb = wh + (size_t)arow * K_DIM + acol;  // +p*32 rows per pass

  float4_ acc[2][4];
  const float4_ fzero = {0.f, 0.f, 0.f, 0.f};
#pragma unroll
  for (int i = 0; i < 2; ++i)
#pragma unroll
    for (int j = 0; j < 4; ++j) acc[i][j] = fzero;

  for (int kt = 0; kt < K_DIM / BK; ++kt) {
    const int k0 = kt * BK;

    // ---- stage A tile (fp32 -> f16) : 32 x 64 ----
    float4_ f0 = *(const float4_*)(xg + k0);
    float4_ f1 = *(const float4_*)(xg + k0 + 4);
    half8 ah;
    ah[0] = (_Float16)f0[0]; ah[1] = (_Float16)f0[1];
    ah[2] = (_Float16)f0[2]; ah[3] = (_Float16)f0[3];
    ah[4] = (_Float16)f1[0]; ah[5] = (_Float16)f1[1];
    ah[6] = (_Float16)f1[2]; ah[7] = (_Float16)f1[3];
    *(half8*)(&As[arow][acol]) = ah;

    // ---- stage B tile (f16) : 256 x 64, 8 passes of 32 rows ----
#pragma unroll
    for (int p = 0; p < 8; ++p) {
      uint4_ v = *(const uint4_*)(wgb + (size_t)p * 32 * K_DIM + k0);
      *(uint4_*)(&Bs[p * 32 + arow][acol]) = v;
    }
    __syncthreads();

    // ---- MFMA: 2 k-subtiles of 32 ----
#pragma unroll
    for (int ks = 0; ks < 2; ++ks) {
      const int koff = ks * 32 + quad * 8;
      half8 a0 = *(const half8*)(&As[l16][koff]);
      half8 a1 = *(const half8*)(&As[l16 + 16][koff]);
      half8 b0 = *(const half8*)(&Bs[wv * 64 + l16][koff]);
      half8 b1 = *(const half8*)(&Bs[wv * 64 + 16 + l16][koff]);
      half8 b2 = *(const half8*)(&Bs[wv * 64 + 32 + l16][koff]);
      half8 b3 = *(const half8*)(&Bs[wv * 64 + 48 + l16][koff]);
      acc[0][0] = __builtin_amdgcn_mfma_f32_16x16x32_f16(a0, b0, acc[0][0], 0, 0, 0);
      acc[1][0] = __builtin_amdgcn_mfma_f32_16x16x32_f16(a1, b0, acc[1][0], 0, 0, 0);
      acc[0][1] = __builtin_amdgcn_mfma_f32_16x16x32_f16(a0, b1, acc[0][1], 0, 0, 0);
      acc[1][1] = __builtin_amdgcn_mfma_f32_16x16x32_f16(a1, b1, acc[1][1], 0, 0, 0);
      acc[0][2] = __builtin_amdgcn_mfma_f32_16x16x32_f16(a0, b2, acc[0][2], 0, 0, 0);
      acc[1][2] = __builtin_amdgcn_mfma_f32_16x16x32_f16(a1, b2, acc[1][2], 0, 0, 0);
      acc[0][3] = __builtin_amdgcn_mfma_f32_16x16x32_f16(a0, b3, acc[0][3], 0, 0, 0);
      acc[1][3] = __builtin_amdgcn_mfma_f32_16x16x32_f16(a1, b3, acc[1][3], 0, 0, 0);
    }
    __syncthreads();
  }

  // ---- epilogue: acc -> LDS S-tile ----
  // C/D layout (verified m89/m91): n = lane&15, m = quad*4 + reg
  float* Sb = (float*)smem;
#pragma unroll
  for (int mf = 0; mf < 2; ++mf)
#pragma unroll
    for (int nf = 0; nf < 4; ++nf)
#pragma unroll
      for (int r = 0; r < 4; ++r)
        Sb[(mf * 16 + quad * 4 + r) * S_LD + wv * 64 + nf * 16 + l16] = acc[mf][nf][r];
  __syncthreads();

  // ---- broadcast-expand with bias: out[m0+m][j] = S[m][j&255] + bias[j] ----
  // thread t writes float4 j4 = c*256 + t  (j = j4*4); j&255 -> S float4 (t&63)
  float4_ bv[4];
  const float4_* bias4 = (const float4_*)bias;
#pragma unroll
  for (int c = 0; c < 4; ++c) bv[c] = bias4[c * 256 + tid];

  const int sc = (tid & 63) * 4;
#pragma unroll 2
  for (int m = 0; m < BM; ++m) {
    float4_ s4 = *(const float4_*)(&Sb[m * S_LD + sc]);
    float4_* orow = (float4_*)(out + (size_t)(m0 + m) * OUT_F);
#pragma unroll
    for (int c = 0; c < 4; ++c) {
      orow[c * 256 + tid] = s4 + bv[c];
    }
  }
}

// ---------------------------------------------------------------------------
extern "C" void kernel_launch(void* const* d_in, const int* in_sizes, int n_in,
                              void* d_out, int out_size, void* d_ws, size_t ws_size,
                              hipStream_t stream) {
  const float* x    = (const float*)d_in[0];
  const float* w    = (const float*)d_in[1];
  const float* bias = (const float*)d_in[2];
  float* out        = (float*)d_out;
  _Float16* wh      = (_Float16*)d_ws;  // 256*4096 f16 = 2 MB

  convert_w_kernel<<<(N_DIM * K_DIM) / (256 * 8), 256, 0, stream>>>(w, wh);
  swfc_kernel<<<M_DIM / BM, 256, 0, stream>>>(x, wh, bias, out);
}

// Round 2
// 278.322 us; speedup vs baseline: 1.0249x; 1.0249x over previous
//
#include <hip/hip_runtime.h>
#include <cstdint>
#include <cstddef>

// Problem constants
#define M_DIM 8192   // batch
#define N_DIM 256    // shared rows (distinct output cols)
#define K_DIM 4096   // in_features
#define OUT_F 4096   // out_features = 16 * N_DIM
// GEMM tiling
#define BM 32
#define BK 64
#define NTH 512      // 8 waves
#define LDK 72       // padded LDS K-stride (halves)
#define S_LD 260     // padded S-tile row stride (floats)

typedef float    float4_  __attribute__((ext_vector_type(4)));
typedef _Float16 half8    __attribute__((ext_vector_type(8)));
typedef _Float16 half4    __attribute__((ext_vector_type(4)));
typedef unsigned int uint4_ __attribute__((ext_vector_type(4)));

// ---------------------------------------------------------------------------
// Kernel 1: convert shared_weights fp32 -> f16 into workspace (2 MB)
// ---------------------------------------------------------------------------
__global__ __launch_bounds__(256) void convert_w_kernel(const float* __restrict__ w,
                                                        _Float16* __restrict__ wh) {
  int i = (blockIdx.x * 256 + threadIdx.x) * 8;
  float4_ f0 = *(const float4_*)(w + i);
  float4_ f1 = *(const float4_*)(w + i + 4);
  half8 h;
  h[0] = (_Float16)f0[0]; h[1] = (_Float16)f0[1];
  h[2] = (_Float16)f0[2]; h[3] = (_Float16)f0[3];
  h[4] = (_Float16)f1[0]; h[5] = (_Float16)f1[1];
  h[6] = (_Float16)f1[2]; h[7] = (_Float16)f1[3];
  *(half8*)(wh + i) = h;
}

// ---------------------------------------------------------------------------
// Kernel 2: fused S = x @ W^T (MFMA f16) + broadcast-expand + bias -> out
// 512 threads = 8 waves. Wave w owns n-slice [w*32, w*32+32): 2 m-frags x
// 2 n-frags of 16x16x32. Register-prefetch pipeline hides HBM latency.
// ---------------------------------------------------------------------------
__global__ __launch_bounds__(512, 2) void swfc_kernel(const float* __restrict__ x,
                                                      const _Float16* __restrict__ wh,
                                                      const float* __restrict__ bias,
                                                      float* __restrict__ out) {
  // As 32x72 f16 (4608 B) + Bs 256x72 f16 (36864 B) = 41472 B
  // epilogue reuses as Sb 32x260 f32 (33280 B)
  __shared__ __align__(16) unsigned char smem[41472];
  _Float16 (*As)[LDK] = (_Float16(*)[LDK])smem;
  _Float16 (*Bs)[LDK] = (_Float16(*)[LDK])(smem + BM * LDK * 2);

  const int tid  = threadIdx.x;
  const int wv   = tid >> 6;        // wave 0..7
  const int lane = tid & 63;
  const int quad = lane >> 4;       // 0..3
  const int l16  = lane & 15;
  const int n0   = wv * 32;         // wave's n-slice base
  const int m0   = blockIdx.x * BM;

  // ---- staging coordinates ----
  // A: thread t -> row t>>4 (0..31), 4 floats at col (t&15)*4
  const int arow = tid >> 4;
  const int acol = (tid & 15) * 4;
  const float* xg = x + (size_t)(m0 + arow) * K_DIM + acol;
  // B: thread t -> row t>>3 (0..63) + p*64, 8 halves at col (t&7)*8
  const int brow = tid >> 3;
  const int bcol = (tid & 7) * 8;
  const _Float16* wgb = wh + (size_t)brow * K_DIM + bcol;

  float4_ acc[2][2];
  const float4_ fzero = {0.f, 0.f, 0.f, 0.f};
#pragma unroll
  for (int i = 0; i < 2; ++i)
#pragma unroll
    for (int j = 0; j < 2; ++j) acc[i][j] = fzero;

  // ---- initial prefetch (k-tile 0) ----
  float4_ aPre = *(const float4_*)(xg);
  uint4_ bPre[4];
#pragma unroll
  for (int p = 0; p < 4; ++p)
    bPre[p] = *(const uint4_*)(wgb + (size_t)p * 64 * K_DIM);

  for (int kt = 0; kt < K_DIM / BK; ++kt) {
    // ---- stage prefetched regs -> LDS ----
    half4 ah;
    ah[0] = (_Float16)aPre[0]; ah[1] = (_Float16)aPre[1];
    ah[2] = (_Float16)aPre[2]; ah[3] = (_Float16)aPre[3];
    *(half4*)(&As[arow][acol]) = ah;
#pragma unroll
    for (int p = 0; p < 4; ++p)
      *(uint4_*)(&Bs[p * 64 + brow][bcol]) = bPre[p];
    __syncthreads();

    // ---- prefetch next k-tile into regs (latency overlaps MFMA below) ----
    if (kt < K_DIM / BK - 1) {
      const int k1 = (kt + 1) * BK;
      aPre = *(const float4_*)(xg + k1);
#pragma unroll
      for (int p = 0; p < 4; ++p)
        bPre[p] = *(const uint4_*)(wgb + (size_t)p * 64 * K_DIM + k1);
    }

    // ---- MFMA: 2 k-subtiles of 32 ----
#pragma unroll
    for (int ks = 0; ks < 2; ++ks) {
      const int koff = ks * 32 + quad * 8;
      half8 a0 = *(const half8*)(&As[l16][koff]);
      half8 a1 = *(const half8*)(&As[l16 + 16][koff]);
      half8 b0 = *(const half8*)(&Bs[n0 + l16][koff]);
      half8 b1 = *(const half8*)(&Bs[n0 + 16 + l16][koff]);
      acc[0][0] = __builtin_amdgcn_mfma_f32_16x16x32_f16(a0, b0, acc[0][0], 0, 0, 0);
      acc[1][0] = __builtin_amdgcn_mfma_f32_16x16x32_f16(a1, b0, acc[1][0], 0, 0, 0);
      acc[0][1] = __builtin_amdgcn_mfma_f32_16x16x32_f16(a0, b1, acc[0][1], 0, 0, 0);
      acc[1][1] = __builtin_amdgcn_mfma_f32_16x16x32_f16(a1, b1, acc[1][1], 0, 0, 0);
    }
    __syncthreads();
  }

  // ---- epilogue: acc -> LDS S-tile ----
  // C/D layout (verified m89/m91): n = lane&15, m = quad*4 + reg
  float* Sb = (float*)smem;
#pragma unroll
  for (int mf = 0; mf < 2; ++mf)
#pragma unroll
    for (int nf = 0; nf < 2; ++nf)
#pragma unroll
      for (int r = 0; r < 4; ++r)
        Sb[(mf * 16 + quad * 4 + r) * S_LD + n0 + nf * 16 + l16] = acc[mf][nf][r];
  __syncthreads();

  // ---- broadcast-expand with bias: out[m0+m][j] = S[m][j&255] + bias[j] ----
  // thread t writes float4 j4 = c*512 + t; (j4*4)&255 -> S float4 (t&63)
  float4_ bv[2];
  const float4_* bias4 = (const float4_*)bias;
#pragma unroll
  for (int c = 0; c < 2; ++c) bv[c] = bias4[c * 512 + tid];

  const int sc = (tid & 63) * 4;
#pragma unroll 4
  for (int m = 0; m < BM; ++m) {
    float4_ s4 = *(const float4_*)(&Sb[m * S_LD + sc]);
    float4_* orow = (float4_*)(out + (size_t)(m0 + m) * OUT_F);
#pragma unroll
    for (int c = 0; c < 2; ++c) {
      orow[c * 512 + tid] = s4 + bv[c];
    }
  }
}

// ---------------------------------------------------------------------------
extern "C" void kernel_launch(void* const* d_in, const int* in_sizes, int n_in,
                              void* d_out, int out_size, void* d_ws, size_t ws_size,
                              hipStream_t stream) {
  const float* x    = (const float*)d_in[0];
  const float* w    = (const float*)d_in[1];
  const float* bias = (const float*)d_in[2];
  float* out        = (float*)d_out;
  _Float16* wh      = (_Float16*)d_ws;  // 256*4096 f16 = 2 MB

  convert_w_kernel<<<(N_DIM * K_DIM) / (256 * 8), 256, 0, stream>>>(w, wh);
  swfc_kernel<<<M_DIM / BM, NTH, 0, stream>>>(x, wh, bias, out);
}

// Round 3
// 271.806 us; speedup vs baseline: 1.0494x; 1.0240x over previous
//
#include <hip/hip_runtime.h>
#include <cstdint>
#include <cstddef>

// Problem constants
#define M_DIM 8192   // batch
#define N_DIM 256    // shared rows (distinct output cols)
#define K_DIM 4096   // in_features
#define OUT_F 4096   // out_features = 16 * N_DIM
// GEMM tiling
#define BM 64
#define BK 64
#define NTH 512      // 8 waves: 2 m-wave-groups x 4 n-wave-groups
#define LDK 72       // padded LDS K-stride (halves); 144 B keeps 16B alignment, 2-way-only aliasing

typedef float    float4_  __attribute__((ext_vector_type(4)));
typedef _Float16 half8    __attribute__((ext_vector_type(8)));
typedef _Float16 half4    __attribute__((ext_vector_type(4)));
typedef unsigned int uint4_ __attribute__((ext_vector_type(4)));

// ---------------------------------------------------------------------------
// Kernel 1: convert shared_weights fp32 -> f16 into workspace (2 MB)
// ---------------------------------------------------------------------------
__global__ __launch_bounds__(256) void convert_w_kernel(const float* __restrict__ w,
                                                        _Float16* __restrict__ wh) {
  int i = (blockIdx.x * 256 + threadIdx.x) * 8;
  float4_ f0 = *(const float4_*)(w + i);
  float4_ f1 = *(const float4_*)(w + i + 4);
  half8 h;
  h[0] = (_Float16)f0[0]; h[1] = (_Float16)f0[1];
  h[2] = (_Float16)f0[2]; h[3] = (_Float16)f0[3];
  h[4] = (_Float16)f1[0]; h[5] = (_Float16)f1[1];
  h[6] = (_Float16)f1[2]; h[7] = (_Float16)f1[3];
  *(half8*)(wh + i) = h;
}

// ---------------------------------------------------------------------------
// Kernel 2: partial GEMM  P[ks] = x[:, ks-slice] @ W[:, ks-slice]^T  (f16 MFMA)
// grid = (M/64) x KS. 512 threads = 8 waves; wave (mw,nw) owns a 32m x 64n
// sub-tile: 2 m-frags x 4 n-frags of 16x16x32. Register-prefetch pipeline.
// K-split gives 2 blocks/CU -> independent barrier groups overlap.
// ---------------------------------------------------------------------------
__global__ __launch_bounds__(NTH, 4) void gemm_s_kernel(const float* __restrict__ x,
                                                        const _Float16* __restrict__ wh,
                                                        float* __restrict__ P,
                                                        int nkt) {
  __shared__ __align__(16) _Float16 As[BM][LDK];     //  9216 B
  __shared__ __align__(16) _Float16 Bs[N_DIM][LDK];  // 36864 B  (total 46080)

  const int tid  = threadIdx.x;
  const int wv   = tid >> 6;        // 0..7
  const int lane = tid & 63;
  const int quad = lane >> 4;       // 0..3
  const int l16  = lane & 15;
  const int mw   = wv >> 2;         // 0..1 -> m-offset mw*32
  const int n0   = (wv & 3) * 64;   // wave n-slice base
  const int m0   = blockIdx.x * BM;
  const int kbase = blockIdx.y * nkt * BK;

  // ---- staging coordinates ----
  // A: 64x64 halves. thread t -> row t>>3 (0..63), 8 floats at col (t&7)*8
  const int arow = tid >> 3;
  const int acol = (tid & 7) * 8;
  const float* xg = x + (size_t)(m0 + arow) * K_DIM + kbase + acol;
  // B: 256x64 halves in 4 passes of 64 rows; same row/col split
  const _Float16* wgb = wh + (size_t)arow * K_DIM + kbase + acol;

  float4_ acc[2][4];
  const float4_ fzero = {0.f, 0.f, 0.f, 0.f};
#pragma unroll
  for (int i = 0; i < 2; ++i)
#pragma unroll
    for (int j = 0; j < 4; ++j) acc[i][j] = fzero;

  // ---- initial prefetch (k-tile 0) ----
  float4_ aPre0 = *(const float4_*)(xg);
  float4_ aPre1 = *(const float4_*)(xg + 4);
  uint4_ bPre[4];
#pragma unroll
  for (int p = 0; p < 4; ++p)
    bPre[p] = *(const uint4_*)(wgb + (size_t)p * 64 * K_DIM);

  for (int kt = 0; kt < nkt; ++kt) {
    // ---- stage prefetched regs -> LDS ----
    half8 ah;
    ah[0] = (_Float16)aPre0[0]; ah[1] = (_Float16)aPre0[1];
    ah[2] = (_Float16)aPre0[2]; ah[3] = (_Float16)aPre0[3];
    ah[4] = (_Float16)aPre1[0]; ah[5] = (_Float16)aPre1[1];
    ah[6] = (_Float16)aPre1[2]; ah[7] = (_Float16)aPre1[3];
    *(half8*)(&As[arow][acol]) = ah;
#pragma unroll
    for (int p = 0; p < 4; ++p)
      *(uint4_*)(&Bs[p * 64 + arow][acol]) = bPre[p];
    __syncthreads();

    // ---- prefetch next k-tile into regs (latency overlaps MFMA below) ----
    if (kt + 1 < nkt) {
      const int k1 = (kt + 1) * BK;
      aPre0 = *(const float4_*)(xg + k1);
      aPre1 = *(const float4_*)(xg + k1 + 4);
#pragma unroll
      for (int p = 0; p < 4; ++p)
        bPre[p] = *(const uint4_*)(wgb + (size_t)p * 64 * K_DIM + k1);
    }

    // ---- MFMA: 2 k-subtiles of 32 ----
#pragma unroll
    for (int ks = 0; ks < 2; ++ks) {
      const int koff = ks * 32 + quad * 8;
      half8 a0 = *(const half8*)(&As[mw * 32 + l16][koff]);
      half8 a1 = *(const half8*)(&As[mw * 32 + 16 + l16][koff]);
      half8 b0 = *(const half8*)(&Bs[n0 + l16][koff]);
      half8 b1 = *(const half8*)(&Bs[n0 + 16 + l16][koff]);
      half8 b2 = *(const half8*)(&Bs[n0 + 32 + l16][koff]);
      half8 b3 = *(const half8*)(&Bs[n0 + 48 + l16][koff]);
      acc[0][0] = __builtin_amdgcn_mfma_f32_16x16x32_f16(a0, b0, acc[0][0], 0, 0, 0);
      acc[1][0] = __builtin_amdgcn_mfma_f32_16x16x32_f16(a1, b0, acc[1][0], 0, 0, 0);
      acc[0][1] = __builtin_amdgcn_mfma_f32_16x16x32_f16(a0, b1, acc[0][1], 0, 0, 0);
      acc[1][1] = __builtin_amdgcn_mfma_f32_16x16x32_f16(a1, b1, acc[1][1], 0, 0, 0);
      acc[0][2] = __builtin_amdgcn_mfma_f32_16x16x32_f16(a0, b2, acc[0][2], 0, 0, 0);
      acc[1][2] = __builtin_amdgcn_mfma_f32_16x16x32_f16(a1, b2, acc[1][2], 0, 0, 0);
      acc[0][3] = __builtin_amdgcn_mfma_f32_16x16x32_f16(a0, b3, acc[0][3], 0, 0, 0);
      acc[1][3] = __builtin_amdgcn_mfma_f32_16x16x32_f16(a1, b3, acc[1][3], 0, 0, 0);
    }
    __syncthreads();
  }

  // ---- epilogue: direct partial store (C/D layout: n=lane&15, m=quad*4+r) ----
  float* Pout = P + (size_t)blockIdx.y * (M_DIM * N_DIM);
  const int mbase = m0 + mw * 32 + quad * 4;
  const int nbase = n0 + l16;
#pragma unroll
  for (int mf = 0; mf < 2; ++mf)
#pragma unroll
    for (int nf = 0; nf < 4; ++nf)
#pragma unroll
      for (int r = 0; r < 4; ++r)
        Pout[(size_t)(mbase + mf * 16 + r) * N_DIM + nbase + nf * 16] = acc[mf][nf][r];
}

// ---------------------------------------------------------------------------
// Kernel 3: out[m][j] = sum_ks P[ks][m][j&255] + bias[j]  (pure streaming)
// 1024 blocks x 256 threads; each block does 8 m-rows. Wave-contiguous 1 KB
// writes; bias cached in LDS.
// ---------------------------------------------------------------------------
__global__ __launch_bounds__(256) void expand_kernel(const float* __restrict__ P,
                                                     const float* __restrict__ bias,
                                                     float* __restrict__ out,
                                                     int nks) {
  __shared__ __align__(16) float bsh[OUT_F];
  const int tid = threadIdx.x;
  const float4_* b4 = (const float4_*)bias;
  float4_* bs4 = (float4_*)bsh;
#pragma unroll
  for (int p = 0; p < 4; ++p) bs4[p * 256 + tid] = b4[p * 256 + tid];
  __syncthreads();

  const int ml  = tid >> 6;   // 0..3: m-row within group
  const int c64 = tid & 63;   // float4 index within 256-wide S row
  const float4_* P4 = (const float4_*)P;

#pragma unroll
  for (int pass = 0; pass < 2; ++pass) {
    const int m = blockIdx.x * 8 + pass * 4 + ml;
    float4_ s = {0.f, 0.f, 0.f, 0.f};
    for (int ks = 0; ks < nks; ++ks)
      s += P4[((size_t)ks * M_DIM + m) * (N_DIM / 4) + c64];
    float4_* orow = (float4_*)(out + (size_t)m * OUT_F);
#pragma unroll
    for (int c = 0; c < 16; ++c)
      orow[c * 64 + c64] = s + bs4[c * 64 + c64];
  }
}

// ---------------------------------------------------------------------------
extern "C" void kernel_launch(void* const* d_in, const int* in_sizes, int n_in,
                              void* d_out, int out_size, void* d_ws, size_t ws_size,
                              hipStream_t stream) {
  const float* x    = (const float*)d_in[0];
  const float* w    = (const float*)d_in[1];
  const float* bias = (const float*)d_in[2];
  float* out        = (float*)d_out;
  _Float16* wh      = (_Float16*)d_ws;                       // 2 MB
  float* P          = (float*)((char*)d_ws + (2u << 20));    // KS * 8 MB partials

  const size_t whB    = (size_t)N_DIM * K_DIM * 2;           // 2 MB
  const size_t pslice = (size_t)M_DIM * N_DIM * 4;           // 8 MB
  int KS = (ws_size >= whB + 4 * pslice) ? 4
         : (ws_size >= whB + 2 * pslice) ? 2 : 1;
  int nkt = (K_DIM / BK) / KS;

  convert_w_kernel<<<(N_DIM * K_DIM) / (256 * 8), 256, 0, stream>>>(w, wh);
  gemm_s_kernel<<<dim3(M_DIM / BM, KS), NTH, 0, stream>>>(x, wh, P, nkt);
  expand_kernel<<<M_DIM / 8, 256, 0, stream>>>(P, bias, out, KS);
}